// Round 3
// baseline (462.156 us; speedup 1.0000x reference)
//
#include <hip/hip_runtime.h>
#include <stdint.h>

// ---------- fast transcendentals (v_exp_f32 = 2^x, v_log_f32 = log2, v_rcp_f32) ----------
#define LOG2E 1.4426950408889634f
#define LN2   0.6931471805599453f

__device__ __forceinline__ float fast_tanh(float x) {
    // tanh(x) = 1 - 2/(exp(2x)+1); exp2 overflow/underflow saturates correctly
    float e = __builtin_amdgcn_exp2f(x * (2.0f * LOG2E));
    return 1.0f - 2.0f * __builtin_amdgcn_rcpf(e + 1.0f);
}
__device__ __forceinline__ float fast_softplus(float x) {
    // log(1+exp(x)) = max(x,0) + log1p(exp(-|x|))  (overflow-safe)
    float ax = fabsf(x);
    float t = LN2 * __builtin_amdgcn_logf(1.0f + __builtin_amdgcn_exp2f(-LOG2E * ax));
    return fmaxf(x, 0.0f) + t;
}
__device__ __forceinline__ float fast_ln(float x) {
    return LN2 * __builtin_amdgcn_logf(x);
}

// uniform load pinned to SGPR
__device__ __forceinline__ float uload(const float* __restrict__ p) {
    return __int_as_float(__builtin_amdgcn_readfirstlane(__float_as_int(*p)));
}

// ---------- weight prep: fp32 -> fp32 (+softplus where reparameterized) ----------
// ws layout (floats):
//   [0..71]    f1_W            [72..79]   f1_b
//   [80..143]  f2_0_W          [144..151] f2_0_b
//   [152..159] sp(f2tau_W)     [160..167] sp(f2tau_b)
//   [168..231] sp(f2_1_W)      [232..239] sp(f2_1_b)
//   [240..247] sp(f2_2_W)      [248]      sp(f2_2_b)
__global__ void prep_kernel(
    const float* __restrict__ f1W,  const float* __restrict__ f1b,
    const float* __restrict__ f2tW, const float* __restrict__ f2tb,
    const float* __restrict__ f20W, const float* __restrict__ f20b,
    const float* __restrict__ f21W, const float* __restrict__ f21b,
    const float* __restrict__ f22W, const float* __restrict__ f22b,
    float* __restrict__ w)
{
    int t = threadIdx.x;
    if (t < 72) w[t]        = f1W[t];
    if (t < 8)  w[72 + t]   = f1b[t];
    if (t < 64) w[80 + t]   = f20W[t];
    if (t < 8)  w[144 + t]  = f20b[t];
    if (t < 8)  w[152 + t]  = fast_softplus(f2tW[t]);
    if (t < 8)  w[160 + t]  = fast_softplus(f2tb[t]);
    if (t < 64) w[168 + t]  = fast_softplus(f21W[t]);
    if (t < 8)  w[232 + t]  = fast_softplus(f21b[t]);
    if (t < 8)  w[240 + t]  = fast_softplus(f22W[t]);
    if (t == 0) w[248]      = fast_softplus(f22b[0]);
}

// ---------- main kernel: one thread per row ----------
__global__ void __launch_bounds__(256) haz_kernel(
    const float* __restrict__ Y,
    const float* __restrict__ tau,
    const float* __restrict__ w,
    float* __restrict__ out,
    int n)
{
    int i = blockIdx.x * blockDim.x + threadIdx.x;
    if (i >= n) return;

    // Y row: 16 fp32 = 64 B, four 16B vector loads
    union { float4 v[4]; float s[16]; } u;
    const float4* yp = (const float4*)(Y + (size_t)i * 16);
    u.v[0] = yp[0];
    u.v[1] = yp[1];
    u.v[2] = yp[2];
    u.v[3] = yp[3];

    // Y_diff = log(diff(Y[:, -13:]) + 0.1); scan consumes first 11 diffs
    // cols 3..14 feed diffs 0..10
    float yd[11];
    #pragma unroll
    for (int j = 0; j < 11; ++j)
        yd[j] = fast_ln(u.s[4 + j] - u.s[3 + j] + 0.1f);

    // pin f1 weights (hot-loop operands) to SGPRs
    float f1W[72], f1b[8];
    #pragma unroll
    for (int k = 0; k < 72; ++k) f1W[k] = uload(w + k);
    #pragma unroll
    for (int k = 0; k < 8; ++k)  f1b[k] = uload(w + 72 + k);

    // recurrent f1: 11 steps of tanh(Linear(9->8))
    float flow[8];
    #pragma unroll
    for (int k = 0; k < 8; ++k) flow[k] = 0.0f;

    #pragma unroll
    for (int t = 0; t < 11; ++t) {
        float nf[8];
        #pragma unroll
        for (int o = 0; o < 8; ++o) {
            float acc = f1b[o];
            #pragma unroll
            for (int k = 0; k < 8; ++k) acc = fmaf(f1W[o * 9 + k], flow[k], acc);
            acc = fmaf(f1W[o * 9 + 8], yd[t], acc);
            nf[o] = fast_tanh(acc);
        }
        #pragma unroll
        for (int o = 0; o < 8; ++o) flow[o] = nf[o];
    }

    // f2 layer 0: tanh(flow @ W0.T + b0 + tau*sp(Wt) + sp(bt))
    float tv = tau[i];
    float h[8];
    #pragma unroll
    for (int o = 0; o < 8; ++o) {
        float acc = uload(w + 144 + o) + tv * uload(w + 152 + o) + uload(w + 160 + o);
        #pragma unroll
        for (int k = 0; k < 8; ++k) acc = fmaf(uload(w + 80 + o * 8 + k), flow[k], acc);
        h[o] = fast_tanh(acc);
    }
    // f2 layer 1: tanh(h @ sp(W1).T + sp(b1))
    float g[8];
    #pragma unroll
    for (int o = 0; o < 8; ++o) {
        float acc = uload(w + 232 + o);
        #pragma unroll
        for (int k = 0; k < 8; ++k) acc = fmaf(uload(w + 168 + o * 8 + k), h[k], acc);
        g[o] = fast_tanh(acc);
    }
    // output layer + softplus
    float z = uload(w + 248);
    #pragma unroll
    for (int k = 0; k < 8; ++k) z = fmaf(uload(w + 240 + k), g[k], z);

    out[i] = fast_softplus(z);
}

extern "C" void kernel_launch(void* const* d_in, const int* in_sizes, int n_in,
                              void* d_out, int out_size, void* d_ws, size_t ws_size,
                              hipStream_t stream)
{
    const float* Y   = (const float*)d_in[0];
    const float* tau = (const float*)d_in[1];
    float* w = (float*)d_ws;
    float* out = (float*)d_out;
    int n = in_sizes[1];  // tau_vec has N elements

    prep_kernel<<<1, 128, 0, stream>>>(
        (const float*)d_in[2],  (const float*)d_in[3],
        (const float*)d_in[4],  (const float*)d_in[5],
        (const float*)d_in[6],  (const float*)d_in[7],
        (const float*)d_in[8],  (const float*)d_in[9],
        (const float*)d_in[10], (const float*)d_in[11],
        w);

    haz_kernel<<<(n + 255) / 256, 256, 0, stream>>>(Y, tau, w, out, n);
}